// Round 7
// baseline (372.439 us; speedup 1.0000x reference)
//
#include <hip/hip_runtime.h>
#include <stdint.h>

// Problem constants
#define BATCH   2048
#define KBITS   14
#define MROW    16384  // fp32 mem row entries (2^14)
#define BROW    128    // unified bit-row: h_in[0..63] | state[64..95] | s_out[96..127]
#define PAD     129    // LDS padded stride: bank=(lane+wd)&31 -> 2-way (free)

// pack_bits block ranges (each thread packs 8 entries -> 1 byte store)
#define BLK_IN  4096   // 8,388,608 ints / 8 / 256
#define BLK_ST  1024   // 2,097,152 ints / 8 / 256

// ---------------------------------------------------------------------------
// Entry-order byte pack for input_bits and state_bits only (40 MB read).
// Thread t packs entries 8t..8t+7 into one byte (coalesced 64B/wave stores).
// Little-endian: entry e sits at bit (e&31) of u32 word (e>>5).
__global__ __launch_bounds__(256) void pack_bits(const int4* __restrict__ inb,
                                                 const int4* __restrict__ stb,
                                                 uint8_t* __restrict__ bits1_b,
                                                 uint8_t* __restrict__ buf_b) {
    const int blk = blockIdx.x;
    if (blk < BLK_IN) {                         // input_bits -> bits1 (flat)
        const long t = (long)blk * 256 + threadIdx.x;
        const int4* p = inb + (t << 1);
        int4 a = p[0], b = p[1];
        uint32_t w = (uint32_t)(a.x == 1)        | ((uint32_t)(a.y == 1) << 1) |
                     ((uint32_t)(a.z == 1) << 2) | ((uint32_t)(a.w == 1) << 3) |
                     ((uint32_t)(b.x == 1) << 4) | ((uint32_t)(b.y == 1) << 5) |
                     ((uint32_t)(b.z == 1) << 6) | ((uint32_t)(b.w == 1) << 7);
        bits1_b[t] = (uint8_t)w;
    } else {                                    // state_bits -> buf bytes 256..383
        const long t = (long)(blk - BLK_IN) * 256 + threadIdx.x;
        const int4* p = stb + (t << 1);
        int4 a = p[0], b = p[1];
        uint32_t w = (uint32_t)(a.x == 1)        | ((uint32_t)(a.y == 1) << 1) |
                     ((uint32_t)(a.z == 1) << 2) | ((uint32_t)(a.w == 1) << 3) |
                     ((uint32_t)(b.x == 1) << 4) | ((uint32_t)(b.y == 1) << 5) |
                     ((uint32_t)(b.z == 1) << 6) | ((uint32_t)(b.w == 1) << 7);
        const long row = t >> 7;                // 128 state bytes per row
        const long col = t & 127;
        buf_b[row * 512 + 256 + col] = (uint8_t)w;
    }
}

// ---------------------------------------------------------------------------
// RAM layer, lane = batch row; 64 rows staged in LDS (stride 129 -> 2-way
// free). Wave handles NW consecutive neurons, conn wave-uniform (s_load).
// Phase A: NW 14-bit addresses from LDS bit-extracts (k=0 is MSB).
// Phase B: NW INDEPENDENT float gathers DIRECTLY from the fp32 table
//          (row = 64 KB; just restored by harness -> L3-resident).
// Phase C: bit = (val==1.0f), ballot over batch, 64x64 bit transpose.
// MODE 0: u16 store to buf words 0..63   (h_in,  NW=16)
// MODE 1: u8  store to buf words 96..127 (s_out, NW=8)
// MODE 2: float4 output direct           (out,   NW=8; idx>=2048 -> +32 words)
template <int NW, int MODE>
__global__ __launch_bounds__(256) void ram_layer(const uint32_t* __restrict__ src,
                                                 const int* __restrict__ conn,
                                                 const float* __restrict__ mem,
                                                 uint32_t* __restrict__ dst,
                                                 float* __restrict__ fout) {
    __shared__ uint32_t lds[64 * PAD];
    const int tid = threadIdx.x;
    const int b0 = blockIdx.y * 64;
    {
        const uint4* g = (const uint4*)(src + (long)b0 * BROW);
        for (int v = tid; v < 64 * BROW / 4; v += 256) {
            uint4 d = g[v];
            int row = v >> 5;
            int col = (v & 31) * 4;
            uint32_t* p = lds + row * PAD + col;
            p[0] = d.x; p[1] = d.y; p[2] = d.z; p[3] = d.w;
        }
    }
    __syncthreads();

    const int lane = tid & 63;
    const int wv = __builtin_amdgcn_readfirstlane(tid >> 6);
    const int n0 = blockIdx.x * (4 * NW) + wv * NW;
    const uint32_t* myrow = lds + lane * PAD;

    // Phase A: addresses
    uint32_t addr[NW];
#pragma unroll
    for (int i = 0; i < NW; ++i) {
        const int* c = conn + (n0 + i) * KBITS;
        uint32_t a = 0;
#pragma unroll
        for (int k = 0; k < KBITS; k++) {
            int idx = c[k];
            int wd = idx >> 5;
            if (MODE == 2 && idx >= 2048) wd += 32;   // o_inp: s_out region
            a = (a << 1) | ((myrow[wd] >> (idx & 31)) & 1u);
        }
        addr[i] = a;
    }
    // Phase B: independent direct fp32 gathers (NW loads in flight)
    float val[NW];
#pragma unroll
    for (int i = 0; i < NW; ++i)
        val[i] = mem[(long)(n0 + i) * MROW + addr[i]];
    // Phase C: ballots + select
    unsigned long long msk = 0;
#pragma unroll
    for (int i = 0; i < NW; ++i) {
        unsigned long long m = __ballot(val[i] == 1.0f);
        msk = (lane == i) ? m : msk;
    }

    // 64x64 bit transpose across lanes.
    unsigned long long x = msk;
#define TSTEP(S, M)                                                         \
    {                                                                       \
        unsigned long long t =                                              \
            (unsigned long long)__shfl_xor((long long)x, S, 64);            \
        x = (lane & S) ? ((x & ~(M)) | ((t & ~(M)) >> S))                   \
                       : ((x & (M)) | ((t & (M)) << S));                    \
    }
    TSTEP(32, 0x00000000ffffffffULL)
    TSTEP(16, 0x0000ffff0000ffffULL)
    TSTEP(8,  0x00ff00ff00ff00ffULL)
    TSTEP(4,  0x0f0f0f0f0f0f0f0fULL)
    TSTEP(2,  0x3333333333333333ULL)
    TSTEP(1,  0x5555555555555555ULL)
#undef TSTEP

    // lane b holds bits for neurons n0..n0+NW-1 of batch row b0+b.
    if (MODE == 0) {
        ((uint16_t*)(dst + (long)(b0 + lane) * BROW))[n0 >> 4] = (uint16_t)x;
    } else if (MODE == 1) {
        ((uint8_t*)(dst + (long)(b0 + lane) * BROW + 96))[n0 >> 3] = (uint8_t)x;
    } else {
        float* o = fout + (long)(b0 + lane) * 1024 + n0;
        float4 f0, f1;
        f0.x = (float)((x >> 0) & 1); f0.y = (float)((x >> 1) & 1);
        f0.z = (float)((x >> 2) & 1); f0.w = (float)((x >> 3) & 1);
        f1.x = (float)((x >> 4) & 1); f1.y = (float)((x >> 5) & 1);
        f1.z = (float)((x >> 6) & 1); f1.w = (float)((x >> 7) & 1);
        ((float4*)o)[0] = f0;
        ((float4*)o)[1] = f1;
    }
}

// ---------------------------------------------------------------------------
extern "C" void kernel_launch(void* const* d_in, const int* in_sizes, int n_in,
                              void* d_out, int out_size, void* d_ws, size_t ws_size,
                              hipStream_t stream) {
    const int*   input_bits = (const int*)d_in[0];
    const int*   state_bits = (const int*)d_in[1];
    const int*   in_conn    = (const int*)d_in[2];
    const float* in_mem     = (const float*)d_in[3];
    const int*   st_conn    = (const int*)d_in[4];
    const float* st_mem     = (const float*)d_in[5];
    const int*   out_conn   = (const int*)d_in[6];
    const float* out_mem    = (const float*)d_in[7];
    float*       out        = (float*)d_out;

    // Workspace: bits1 [B][128] @0 (1MB) | buf [B][128] @1MB (1MB); no tables.
    char* ws = (char*)d_ws;
    uint32_t* bits1 = (uint32_t*)(ws);
    uint32_t* buf   = (uint32_t*)(ws + 1048576);

    // Pack only input/state bits (40 MB read, ~15 us).
    pack_bits<<<BLK_IN + BLK_ST, 256, 0, stream>>>(
        (const int4*)input_bits, (const int4*)state_bits,
        (uint8_t*)bits1, (uint8_t*)buf);

    // Layer 1: bits1 -> h_in (buf words 0..63), direct gathers from in_mem
    ram_layer<16, 0><<<dim3(32, 32), 256, 0, stream>>>(bits1, in_conn, in_mem, buf, nullptr);
    // Layer 2: buf(h_in|state) -> s_out (buf words 96..127)
    ram_layer<8, 1><<<dim3(32, 32), 256, 0, stream>>>(buf, st_conn, st_mem, buf, nullptr);
    // Layer 3: buf(h_in|s_out) -> float output
    ram_layer<8, 2><<<dim3(32, 32), 256, 0, stream>>>(buf, out_conn, out_mem, nullptr, out);
}